// Round 1
// baseline (2173.462 us; speedup 1.0000x reference)
//
#include <hip/hip_runtime.h>
#include <math.h>

#define DIM 128

// Kernel 1: zero the out matrix region AND accumulate sim reduction terms.
// i indexes [0, BATCH*DIM). b = i/128, d = i%128.
// Accumulates sum(x*y), sum(x*x), sum(y*y) into acc[0..2] (doubles).
__global__ void zero_sim_kernel(const float* __restrict__ inputs,
                                const float* __restrict__ old_act,
                                const int* __restrict__ fields,
                                float* __restrict__ out,
                                double* __restrict__ acc,
                                int n) {
    int i = blockIdx.x * blockDim.x + threadIdx.x;
    float x = 0.f, y = 0.f;
    if (i < n) {
        out[i] = 0.f;
        int b = i >> 7;
        int d = i & (DIM - 1);
        x = inputs[i];
        int f = fields[b];
        y = old_act[(size_t)f * DIM + d];
    }
    float dot = x * y, nx = x * x, ny = y * y;
    // wave(64) butterfly reduce
    for (int off = 32; off > 0; off >>= 1) {
        dot += __shfl_down(dot, off, 64);
        nx  += __shfl_down(nx,  off, 64);
        ny  += __shfl_down(ny,  off, 64);
    }
    __shared__ float s[3][4];
    int lane = threadIdx.x & 63;
    int wv   = threadIdx.x >> 6;
    if (lane == 0) { s[0][wv] = dot; s[1][wv] = nx; s[2][wv] = ny; }
    __syncthreads();
    if (threadIdx.x == 0) {
        float D = 0.f, NX = 0.f, NY = 0.f;
        for (int w = 0; w < 4; ++w) { D += s[0][w]; NX += s[1][w]; NY += s[2][w]; }
        atomicAdd(&acc[0], (double)D);
        atomicAdd(&acc[1], (double)NX);
        atomicAdd(&acc[2], (double)NY);
    }
}

// Kernel 2: subsampled_support @ diff. One wave per edge, 2 floats/lane.
// diff[col] = inputs[col] - old_act[fields[col]]  (computed on the fly).
__global__ void spmm_sub_kernel(const int* __restrict__ rows,
                                const int* __restrict__ cols,
                                const float* __restrict__ vals,
                                const float* __restrict__ inputs,
                                const float* __restrict__ old_act,
                                const int* __restrict__ fields,
                                float* __restrict__ out,
                                int ne) {
    int t = blockIdx.x * blockDim.x + threadIdx.x;
    int e = t >> 6;
    int lane = t & 63;
    if (e >= ne) return;
    int r = rows[e];
    int c = cols[e];
    float v = vals[e];
    int f = fields[c];
    int d0 = lane * 2;
    const float2 x = *(const float2*)(inputs  + (size_t)c * DIM + d0);
    const float2 y = *(const float2*)(old_act + (size_t)f * DIM + d0);
    float* o = out + (size_t)r * DIM + d0;
    atomicAdd(o,     v * (x.x - y.x));
    atomicAdd(o + 1, v * (x.y - y.y));
}

// Kernel 3: support @ old_activation. One wave per edge, 2 floats/lane.
__global__ void spmm_sup_kernel(const int* __restrict__ rows,
                                const int* __restrict__ cols,
                                const float* __restrict__ vals,
                                const float* __restrict__ old_act,
                                float* __restrict__ out,
                                int ne) {
    int t = blockIdx.x * blockDim.x + threadIdx.x;
    int e = t >> 6;
    int lane = t & 63;
    if (e >= ne) return;
    int r = rows[e];
    int c = cols[e];
    float v = vals[e];
    int d0 = lane * 2;
    const float2 y = *(const float2*)(old_act + (size_t)c * DIM + d0);
    float* o = out + (size_t)r * DIM + d0;
    atomicAdd(o,     v * y.x);
    atomicAdd(o + 1, v * y.y);
}

// Kernel 4: sim = dot / (||x|| * ||y||)
__global__ void finalize_kernel(const double* __restrict__ acc,
                                float* __restrict__ out_sim) {
    if (threadIdx.x == 0) {
        double s = acc[0] / (sqrt(acc[1]) * sqrt(acc[2]));
        *out_sim = (float)s;
    }
}

extern "C" void kernel_launch(void* const* d_in, const int* in_sizes, int n_in,
                              void* d_out, int out_size, void* d_ws, size_t ws_size,
                              hipStream_t stream) {
    const float* inputs   = (const float*)d_in[0];
    const float* old_act  = (const float*)d_in[1];
    const int*   fields   = (const int*)d_in[2];
    const int*   sub_rows = (const int*)d_in[3];
    const int*   sub_cols = (const int*)d_in[4];
    const float* sub_vals = (const float*)d_in[5];
    const int*   sup_rows = (const int*)d_in[6];
    const int*   sup_cols = (const int*)d_in[7];
    const float* sup_vals = (const float*)d_in[8];

    const int n     = in_sizes[0];   // BATCH * DIM = 5,120,000
    const int e_sub = in_sizes[3];   // 320,000
    const int e_sup = in_sizes[6];   // 1,280,000

    float*  out = (float*)d_out;
    double* acc = (double*)d_ws;     // acc[0..2]: dot, |x|^2, |y|^2

    hipMemsetAsync(d_ws, 0, 3 * sizeof(double), stream);

    zero_sim_kernel<<<(n + 255) / 256, 256, 0, stream>>>(
        inputs, old_act, fields, out, acc, n);

    // one wave (64 threads) per edge
    {
        long long threads = (long long)e_sub * 64;
        int blocks = (int)((threads + 255) / 256);
        spmm_sub_kernel<<<blocks, 256, 0, stream>>>(
            sub_rows, sub_cols, sub_vals, inputs, old_act, fields, out, e_sub);
    }
    {
        long long threads = (long long)e_sup * 64;
        int blocks = (int)((threads + 255) / 256);
        spmm_sup_kernel<<<blocks, 256, 0, stream>>>(
            sup_rows, sup_cols, sup_vals, old_act, out, e_sup);
    }

    finalize_kernel<<<1, 64, 0, stream>>>(acc, out + n);
}

// Round 2
// 1337.682 us; speedup vs baseline: 1.6248x; 1.6248x over previous
//
#include <hip/hip_runtime.h>
#include <math.h>

#define DIM 128

// ---------------- sim reduction (no out zeroing needed: row kernel writes every row) ---
__global__ void sim_kernel(const float* __restrict__ inputs,
                           const float* __restrict__ old_act,
                           const int* __restrict__ fields,
                           double* __restrict__ acc,
                           int n) {
    int i = blockIdx.x * blockDim.x + threadIdx.x;
    float x = 0.f, y = 0.f;
    if (i < n) {
        int b = i >> 7;
        int d = i & (DIM - 1);
        x = inputs[i];
        int f = fields[b];
        y = old_act[(size_t)f * DIM + d];
    }
    float dot = x * y, nx = x * x, ny = y * y;
    for (int off = 32; off > 0; off >>= 1) {
        dot += __shfl_down(dot, off, 64);
        nx  += __shfl_down(nx,  off, 64);
        ny  += __shfl_down(ny,  off, 64);
    }
    __shared__ float s[3][4];
    int lane = threadIdx.x & 63;
    int wv   = threadIdx.x >> 6;
    if (lane == 0) { s[0][wv] = dot; s[1][wv] = nx; s[2][wv] = ny; }
    __syncthreads();
    if (threadIdx.x == 0) {
        float D = 0.f, NX = 0.f, NY = 0.f;
        for (int w = 0; w < 4; ++w) { D += s[0][w]; NX += s[1][w]; NY += s[2][w]; }
        atomicAdd(&acc[0], (double)D);
        atomicAdd(&acc[1], (double)NX);
        atomicAdd(&acc[2], (double)NY);
    }
}

__global__ void finalize_kernel(const double* __restrict__ acc,
                                float* __restrict__ out_sim) {
    if (threadIdx.x == 0) {
        double s = acc[0] / (sqrt(acc[1]) * sqrt(acc[2]));
        *out_sim = (float)s;
    }
}

// ---------------- counting-sort machinery ----------------
__global__ void hist_kernel(const int* __restrict__ rows, int* __restrict__ cnt, int ne) {
    int i = blockIdx.x * blockDim.x + threadIdx.x;
    if (i < ne) atomicAdd(&cnt[rows[i]], 1);
}

// One block per array (gridDim.x == 2). 1024 threads, chunked serial + LDS scan.
__global__ void scan_kernel(const int* __restrict__ cnt0, int* __restrict__ off0, int* __restrict__ cur0,
                            const int* __restrict__ cnt1, int* __restrict__ off1, int* __restrict__ cur1,
                            int nrows) {
    const int* cnt = blockIdx.x ? cnt1 : cnt0;
    int* off = blockIdx.x ? off1 : off0;
    int* cur = blockIdx.x ? cur1 : cur0;
    __shared__ int s[1024];
    int chunk = (nrows + 1023) >> 10;
    int beg = threadIdx.x * chunk;
    int end = beg + chunk; if (end > nrows) end = nrows;
    int sum = 0;
    for (int i = beg; i < end && i < nrows; ++i) sum += cnt[i];
    s[threadIdx.x] = sum;
    __syncthreads();
    for (int d = 1; d < 1024; d <<= 1) {
        int v = (threadIdx.x >= (unsigned)d) ? s[threadIdx.x - d] : 0;
        __syncthreads();
        s[threadIdx.x] += v;
        __syncthreads();
    }
    int prefix = (threadIdx.x == 0) ? 0 : s[threadIdx.x - 1];
    for (int i = beg; i < end && i < nrows; ++i) {
        off[i] = prefix; cur[i] = prefix;
        prefix += cnt[i];
    }
    if (threadIdx.x == 1023) off[nrows] = s[1023];
}

__global__ void scatter_kernel(const int* __restrict__ rows, const int* __restrict__ cols,
                               const float* __restrict__ vals,
                               int* __restrict__ cur, int2* __restrict__ pk, int ne) {
    int i = blockIdx.x * blockDim.x + threadIdx.x;
    if (i < ne) {
        int pos = atomicAdd(&cur[rows[i]], 1);
        pk[pos] = make_int2(cols[i], __float_as_int(vals[i]));
    }
}

// ---------------- per-row accumulate: one wave per row, zero output atomics ----------
__global__ void row_kernel(const int* __restrict__ off_sub, const int2* __restrict__ pk_sub,
                           const int* __restrict__ off_sup, const int2* __restrict__ pk_sup,
                           const float* __restrict__ inputs, const float* __restrict__ old_act,
                           const int* __restrict__ fields, float* __restrict__ out, int nrows) {
    int wv = threadIdx.x >> 6, lane = threadIdx.x & 63;
    int r = blockIdx.x * (blockDim.x >> 6) + wv;
    if (r >= nrows) return;
    int d0 = lane * 2;
    float a0 = 0.f, a1 = 0.f;

    int b = off_sub[r], e = off_sub[r + 1];
    for (int j = b; j < e; ++j) {
        int2 p = pk_sub[j];
        int c = p.x; float v = __int_as_float(p.y);
        int f = fields[c];
        float2 x = *(const float2*)(inputs  + (size_t)c * DIM + d0);
        float2 y = *(const float2*)(old_act + (size_t)f * DIM + d0);
        a0 += v * (x.x - y.x);
        a1 += v * (x.y - y.y);
    }
    b = off_sup[r]; e = off_sup[r + 1];
    for (int j = b; j < e; ++j) {
        int2 p = pk_sup[j];
        int c = p.x; float v = __int_as_float(p.y);
        float2 y = *(const float2*)(old_act + (size_t)c * DIM + d0);
        a0 += v * y.x;
        a1 += v * y.y;
    }
    *(float2*)(out + (size_t)r * DIM + d0) = make_float2(a0, a1);
}

// ---------------- fallback (round-1 atomic path, if ws too small) ----------
__global__ void zero_out_kernel(float* __restrict__ out, int n) {
    int i = blockIdx.x * blockDim.x + threadIdx.x;
    if (i < n) out[i] = 0.f;
}
__global__ void spmm_sub_atomic(const int* __restrict__ rows, const int* __restrict__ cols,
                                const float* __restrict__ vals, const float* __restrict__ inputs,
                                const float* __restrict__ old_act, const int* __restrict__ fields,
                                float* __restrict__ out, int ne) {
    int t = blockIdx.x * blockDim.x + threadIdx.x;
    int e = t >> 6, lane = t & 63;
    if (e >= ne) return;
    int r = rows[e], c = cols[e];
    float v = vals[e];
    int f = fields[c];
    int d0 = lane * 2;
    const float2 x = *(const float2*)(inputs  + (size_t)c * DIM + d0);
    const float2 y = *(const float2*)(old_act + (size_t)f * DIM + d0);
    float* o = out + (size_t)r * DIM + d0;
    atomicAdd(o,     v * (x.x - y.x));
    atomicAdd(o + 1, v * (x.y - y.y));
}
__global__ void spmm_sup_atomic(const int* __restrict__ rows, const int* __restrict__ cols,
                                const float* __restrict__ vals, const float* __restrict__ old_act,
                                float* __restrict__ out, int ne) {
    int t = blockIdx.x * blockDim.x + threadIdx.x;
    int e = t >> 6, lane = t & 63;
    if (e >= ne) return;
    int r = rows[e], c = cols[e];
    float v = vals[e];
    int d0 = lane * 2;
    const float2 y = *(const float2*)(old_act + (size_t)c * DIM + d0);
    float* o = out + (size_t)r * DIM + d0;
    atomicAdd(o,     v * y.x);
    atomicAdd(o + 1, v * y.y);
}

extern "C" void kernel_launch(void* const* d_in, const int* in_sizes, int n_in,
                              void* d_out, int out_size, void* d_ws, size_t ws_size,
                              hipStream_t stream) {
    const float* inputs   = (const float*)d_in[0];
    const float* old_act  = (const float*)d_in[1];
    const int*   fields   = (const int*)d_in[2];
    const int*   sub_rows = (const int*)d_in[3];
    const int*   sub_cols = (const int*)d_in[4];
    const float* sub_vals = (const float*)d_in[5];
    const int*   sup_rows = (const int*)d_in[6];
    const int*   sup_cols = (const int*)d_in[7];
    const float* sup_vals = (const float*)d_in[8];

    const int n     = in_sizes[0];       // BATCH * DIM
    const int nrows = n / DIM;           // BATCH
    const int e_sub = in_sizes[3];
    const int e_sup = in_sizes[6];

    float*  out = (float*)d_out;
    char*   ws  = (char*)d_ws;

    // ---- workspace layout ----
    size_t off_acc   = 0;                                  // 3 doubles
    size_t off_cnt0  = 64;                                 // cnt_sub [nrows]
    size_t off_cnt1  = off_cnt0 + (size_t)nrows * 4;       // cnt_sup [nrows]
    size_t off_offs0 = off_cnt1 + (size_t)nrows * 4;       // offs_sub [nrows+1]
    size_t off_offs1 = off_offs0 + (size_t)(nrows + 1) * 4;
    size_t off_cur0  = off_offs1 + (size_t)(nrows + 1) * 4;
    size_t off_cur1  = off_cur0 + (size_t)nrows * 4;
    size_t off_pk0   = (off_cur1 + (size_t)nrows * 4 + 7) & ~(size_t)7;  // int2[e_sub]
    size_t off_pk1   = off_pk0 + (size_t)e_sub * 8;                       // int2[e_sup]
    size_t need      = off_pk1 + (size_t)e_sup * 8;

    double* acc = (double*)(ws + off_acc);
    hipMemsetAsync(acc, 0, 3 * sizeof(double), stream);

    sim_kernel<<<(n + 255) / 256, 256, 0, stream>>>(inputs, old_act, fields, acc, n);

    if (ws_size >= need) {
        int* cnt0  = (int*)(ws + off_cnt0);
        int* cnt1  = (int*)(ws + off_cnt1);
        int* offs0 = (int*)(ws + off_offs0);
        int* offs1 = (int*)(ws + off_offs1);
        int* cur0  = (int*)(ws + off_cur0);
        int* cur1  = (int*)(ws + off_cur1);
        int2* pk0  = (int2*)(ws + off_pk0);
        int2* pk1  = (int2*)(ws + off_pk1);

        hipMemsetAsync(cnt0, 0, (size_t)nrows * 8, stream);   // cnt0 + cnt1 contiguous

        hist_kernel<<<(e_sub + 255) / 256, 256, 0, stream>>>(sub_rows, cnt0, e_sub);
        hist_kernel<<<(e_sup + 255) / 256, 256, 0, stream>>>(sup_rows, cnt1, e_sup);

        scan_kernel<<<2, 1024, 0, stream>>>(cnt0, offs0, cur0, cnt1, offs1, cur1, nrows);

        scatter_kernel<<<(e_sub + 255) / 256, 256, 0, stream>>>(sub_rows, sub_cols, sub_vals, cur0, pk0, e_sub);
        scatter_kernel<<<(e_sup + 255) / 256, 256, 0, stream>>>(sup_rows, sup_cols, sup_vals, cur1, pk1, e_sup);

        // 4 waves/block, one wave per row
        row_kernel<<<(nrows + 3) / 4, 256, 0, stream>>>(offs0, pk0, offs1, pk1,
                                                        inputs, old_act, fields, out, nrows);
    } else {
        // fallback: atomic scatter path
        zero_out_kernel<<<(n + 255) / 256, 256, 0, stream>>>(out, n);
        {
            long long threads = (long long)e_sub * 64;
            spmm_sub_atomic<<<(int)((threads + 255) / 256), 256, 0, stream>>>(
                sub_rows, sub_cols, sub_vals, inputs, old_act, fields, out, e_sub);
        }
        {
            long long threads = (long long)e_sup * 64;
            spmm_sup_atomic<<<(int)((threads + 255) / 256), 256, 0, stream>>>(
                sup_rows, sup_cols, sup_vals, old_act, out, e_sup);
        }
    }

    finalize_kernel<<<1, 64, 0, stream>>>(acc, out + n);
}

// Round 3
// 639.442 us; speedup vs baseline: 3.3990x; 2.0920x over previous
//
#include <hip/hip_runtime.h>
#include <math.h>

#define DIM 128
#define SIM_BLOCKS 512

// ---------------- sim: two-stage reduction, NO atomics ----------------
__global__ void sim_partial_kernel(const float* __restrict__ inputs,
                                   const float* __restrict__ old_act,
                                   const int* __restrict__ fields,
                                   float* __restrict__ partials,  // [SIM_BLOCKS*3]
                                   int n2) {                      // n/2 float2 items
    float dot = 0.f, nx = 0.f, ny = 0.f;
    int stride = gridDim.x * blockDim.x;
    for (int i = blockIdx.x * blockDim.x + threadIdx.x; i < n2; i += stride) {
        int idx = i * 2;
        int b = idx >> 7;
        int d = idx & (DIM - 1);
        float2 x = *(const float2*)(inputs + idx);
        int f = fields[b];
        float2 y = *(const float2*)(old_act + (size_t)f * DIM + d);
        dot += x.x * y.x + x.y * y.y;
        nx  += x.x * x.x + x.y * x.y;
        ny  += y.x * y.x + y.y * y.y;
    }
    for (int off = 32; off > 0; off >>= 1) {
        dot += __shfl_down(dot, off, 64);
        nx  += __shfl_down(nx,  off, 64);
        ny  += __shfl_down(ny,  off, 64);
    }
    __shared__ float s[3][4];
    int lane = threadIdx.x & 63;
    int wv   = threadIdx.x >> 6;
    if (lane == 0) { s[0][wv] = dot; s[1][wv] = nx; s[2][wv] = ny; }
    __syncthreads();
    if (threadIdx.x == 0) {
        float D = 0.f, NX = 0.f, NY = 0.f;
        for (int w = 0; w < 4; ++w) { D += s[0][w]; NX += s[1][w]; NY += s[2][w]; }
        partials[blockIdx.x * 3 + 0] = D;
        partials[blockIdx.x * 3 + 1] = NX;
        partials[blockIdx.x * 3 + 2] = NY;
    }
}

// one wave; reduces SIM_BLOCKS partials in double, writes sim scalar
__global__ void finalize_kernel(const float* __restrict__ partials,
                                float* __restrict__ out_sim) {
    double dot = 0.0, nx = 0.0, ny = 0.0;
    for (int i = threadIdx.x; i < SIM_BLOCKS; i += 64) {
        dot += (double)partials[i * 3 + 0];
        nx  += (double)partials[i * 3 + 1];
        ny  += (double)partials[i * 3 + 2];
    }
    for (int off = 32; off > 0; off >>= 1) {
        dot += __shfl_down(dot, off, 64);
        nx  += __shfl_down(nx,  off, 64);
        ny  += __shfl_down(ny,  off, 64);
    }
    if (threadIdx.x == 0)
        *out_sim = (float)(dot / (sqrt(nx) * sqrt(ny)));
}

// ---------------- counting-sort machinery ----------------
// single launch covers both edge lists
__global__ void hist_kernel(const int* __restrict__ rows0, int* __restrict__ cnt0, int ne0,
                            const int* __restrict__ rows1, int* __restrict__ cnt1, int ne1) {
    int i = blockIdx.x * blockDim.x + threadIdx.x;
    if (i < ne0) atomicAdd(&cnt0[rows0[i]], 1);
    if (i < ne1) atomicAdd(&cnt1[rows1[i]], 1);
}

__global__ void scan_kernel(const int* __restrict__ cnt0, int* __restrict__ off0, int* __restrict__ cur0,
                            const int* __restrict__ cnt1, int* __restrict__ off1, int* __restrict__ cur1,
                            int nrows) {
    const int* cnt = blockIdx.x ? cnt1 : cnt0;
    int* off = blockIdx.x ? off1 : off0;
    int* cur = blockIdx.x ? cur1 : cur0;
    __shared__ int s[1024];
    int chunk = (nrows + 1023) >> 10;
    int beg = threadIdx.x * chunk;
    int end = beg + chunk; if (end > nrows) end = nrows;
    int sum = 0;
    for (int i = beg; i < end && i < nrows; ++i) sum += cnt[i];
    s[threadIdx.x] = sum;
    __syncthreads();
    for (int d = 1; d < 1024; d <<= 1) {
        int v = (threadIdx.x >= (unsigned)d) ? s[threadIdx.x - d] : 0;
        __syncthreads();
        s[threadIdx.x] += v;
        __syncthreads();
    }
    int prefix = (threadIdx.x == 0) ? 0 : s[threadIdx.x - 1];
    for (int i = beg; i < end && i < nrows; ++i) {
        off[i] = prefix; cur[i] = prefix;
        prefix += cnt[i];
    }
    if (threadIdx.x == 1023) off[nrows] = s[1023];
}

__global__ void scatter_kernel(const int* __restrict__ rows, const int* __restrict__ cols,
                               const float* __restrict__ vals,
                               int* __restrict__ cur, int2* __restrict__ pk, int ne) {
    int i = blockIdx.x * blockDim.x + threadIdx.x;
    if (i < ne) {
        int pos = atomicAdd(&cur[rows[i]], 1);
        pk[pos] = make_int2(cols[i], __float_as_int(vals[i]));
    }
}

// ---------------- per-row accumulate: one wave per row, zero output atomics ----------
__global__ void row_kernel(const int* __restrict__ off_sub, const int2* __restrict__ pk_sub,
                           const int* __restrict__ off_sup, const int2* __restrict__ pk_sup,
                           const float* __restrict__ inputs, const float* __restrict__ old_act,
                           const int* __restrict__ fields, float* __restrict__ out, int nrows) {
    int wv = threadIdx.x >> 6, lane = threadIdx.x & 63;
    int r = blockIdx.x * (blockDim.x >> 6) + wv;
    if (r >= nrows) return;
    int d0 = lane * 2;
    float a0 = 0.f, a1 = 0.f;

    int b = off_sub[r], e = off_sub[r + 1];
    for (int j = b; j < e; ++j) {
        int2 p = pk_sub[j];
        int c = p.x; float v = __int_as_float(p.y);
        int f = fields[c];
        float2 x = *(const float2*)(inputs  + (size_t)c * DIM + d0);
        float2 y = *(const float2*)(old_act + (size_t)f * DIM + d0);
        a0 += v * (x.x - y.x);
        a1 += v * (x.y - y.y);
    }
    b = off_sup[r]; e = off_sup[r + 1];
    for (int j = b; j < e; ++j) {
        int2 p = pk_sup[j];
        int c = p.x; float v = __int_as_float(p.y);
        float2 y = *(const float2*)(old_act + (size_t)c * DIM + d0);
        a0 += v * y.x;
        a1 += v * y.y;
    }
    *(float2*)(out + (size_t)r * DIM + d0) = make_float2(a0, a1);
}

// ---------------- fallback (atomic path, if ws too small) ----------
__global__ void zero_out_kernel(float* __restrict__ out, int n) {
    int i = blockIdx.x * blockDim.x + threadIdx.x;
    if (i < n) out[i] = 0.f;
}
__global__ void spmm_sub_atomic(const int* __restrict__ rows, const int* __restrict__ cols,
                                const float* __restrict__ vals, const float* __restrict__ inputs,
                                const float* __restrict__ old_act, const int* __restrict__ fields,
                                float* __restrict__ out, int ne) {
    int t = blockIdx.x * blockDim.x + threadIdx.x;
    int e = t >> 6, lane = t & 63;
    if (e >= ne) return;
    int r = rows[e], c = cols[e];
    float v = vals[e];
    int f = fields[c];
    int d0 = lane * 2;
    const float2 x = *(const float2*)(inputs  + (size_t)c * DIM + d0);
    const float2 y = *(const float2*)(old_act + (size_t)f * DIM + d0);
    float* o = out + (size_t)r * DIM + d0;
    atomicAdd(o,     v * (x.x - y.x));
    atomicAdd(o + 1, v * (x.y - y.y));
}
__global__ void spmm_sup_atomic(const int* __restrict__ rows, const int* __restrict__ cols,
                                const float* __restrict__ vals, const float* __restrict__ old_act,
                                float* __restrict__ out, int ne) {
    int t = blockIdx.x * blockDim.x + threadIdx.x;
    int e = t >> 6, lane = t & 63;
    if (e >= ne) return;
    int r = rows[e], c = cols[e];
    float v = vals[e];
    int d0 = lane * 2;
    const float2 y = *(const float2*)(old_act + (size_t)c * DIM + d0);
    float* o = out + (size_t)r * DIM + d0;
    atomicAdd(o,     v * y.x);
    atomicAdd(o + 1, v * y.y);
}

extern "C" void kernel_launch(void* const* d_in, const int* in_sizes, int n_in,
                              void* d_out, int out_size, void* d_ws, size_t ws_size,
                              hipStream_t stream) {
    const float* inputs   = (const float*)d_in[0];
    const float* old_act  = (const float*)d_in[1];
    const int*   fields   = (const int*)d_in[2];
    const int*   sub_rows = (const int*)d_in[3];
    const int*   sub_cols = (const int*)d_in[4];
    const float* sub_vals = (const float*)d_in[5];
    const int*   sup_rows = (const int*)d_in[6];
    const int*   sup_cols = (const int*)d_in[7];
    const float* sup_vals = (const float*)d_in[8];

    const int n     = in_sizes[0];       // BATCH * DIM
    const int nrows = n / DIM;           // BATCH
    const int e_sub = in_sizes[3];
    const int e_sup = in_sizes[6];

    float*  out = (float*)d_out;
    char*   ws  = (char*)d_ws;

    // ---- workspace layout ----
    size_t off_part  = 0;                                   // partials [SIM_BLOCKS*3] f32
    size_t off_cnt0  = (SIM_BLOCKS * 3 * 4 + 63) & ~(size_t)63;
    size_t off_cnt1  = off_cnt0 + (size_t)nrows * 4;
    size_t off_offs0 = off_cnt1 + (size_t)nrows * 4;
    size_t off_offs1 = off_offs0 + (size_t)(nrows + 1) * 4;
    size_t off_cur0  = off_offs1 + (size_t)(nrows + 1) * 4;
    size_t off_cur1  = off_cur0 + (size_t)nrows * 4;
    size_t off_pk0   = (off_cur1 + (size_t)nrows * 4 + 7) & ~(size_t)7;
    size_t off_pk1   = off_pk0 + (size_t)e_sub * 8;
    size_t need      = off_pk1 + (size_t)e_sup * 8;

    float* partials = (float*)(ws + off_part);

    sim_partial_kernel<<<SIM_BLOCKS, 256, 0, stream>>>(inputs, old_act, fields, partials, n / 2);

    if (ws_size >= need) {
        int* cnt0  = (int*)(ws + off_cnt0);
        int* cnt1  = (int*)(ws + off_cnt1);
        int* offs0 = (int*)(ws + off_offs0);
        int* offs1 = (int*)(ws + off_offs1);
        int* cur0  = (int*)(ws + off_cur0);
        int* cur1  = (int*)(ws + off_cur1);
        int2* pk0  = (int2*)(ws + off_pk0);
        int2* pk1  = (int2*)(ws + off_pk1);

        hipMemsetAsync(cnt0, 0, (size_t)nrows * 8, stream);  // cnt0+cnt1 contiguous

        int hist_n = (e_sup > e_sub ? e_sup : e_sub);
        hist_kernel<<<(hist_n + 255) / 256, 256, 0, stream>>>(sub_rows, cnt0, e_sub,
                                                              sup_rows, cnt1, e_sup);

        scan_kernel<<<2, 1024, 0, stream>>>(cnt0, offs0, cur0, cnt1, offs1, cur1, nrows);

        scatter_kernel<<<(e_sub + 255) / 256, 256, 0, stream>>>(sub_rows, sub_cols, sub_vals, cur0, pk0, e_sub);
        scatter_kernel<<<(e_sup + 255) / 256, 256, 0, stream>>>(sup_rows, sup_cols, sup_vals, cur1, pk1, e_sup);

        row_kernel<<<(nrows + 3) / 4, 256, 0, stream>>>(offs0, pk0, offs1, pk1,
                                                        inputs, old_act, fields, out, nrows);
    } else {
        zero_out_kernel<<<(n + 255) / 256, 256, 0, stream>>>(out, n);
        {
            long long threads = (long long)e_sub * 64;
            spmm_sub_atomic<<<(int)((threads + 255) / 256), 256, 0, stream>>>(
                sub_rows, sub_cols, sub_vals, inputs, old_act, fields, out, e_sub);
        }
        {
            long long threads = (long long)e_sup * 64;
            spmm_sup_atomic<<<(int)((threads + 255) / 256), 256, 0, stream>>>(
                sup_rows, sup_cols, sup_vals, old_act, out, e_sup);
        }
    }

    finalize_kernel<<<1, 64, 0, stream>>>(partials, out + n);
}

// Round 4
// 582.471 us; speedup vs baseline: 3.7315x; 1.0978x over previous
//
#include <hip/hip_runtime.h>
#include <math.h>

#define DIM 128
#define SIM_BLOCKS 2048

// ---------------- fused prep: sim partials + row histogram (concatenated) -------------
__global__ void prep_kernel(const float* __restrict__ inputs,
                            const float* __restrict__ old_act,
                            const int* __restrict__ fields,
                            const int* __restrict__ sub_rows, int e_sub,
                            const int* __restrict__ sup_rows, int e_sup,
                            int* __restrict__ cnt,          // [2*nrows], pre-zeroed
                            float* __restrict__ partials,   // [SIM_BLOCKS*3]
                            int nrows, int n2) {
    int tid = blockIdx.x * blockDim.x + threadIdx.x;
    int stride = gridDim.x * blockDim.x;

    // --- sim accumulation over float2 items ---
    float dot = 0.f, nx = 0.f, ny = 0.f;
    for (int i = tid; i < n2; i += stride) {
        int idx = i * 2;
        int b = idx >> 7;
        int d = idx & (DIM - 1);
        float2 x = *(const float2*)(inputs + idx);
        int f = fields[b];
        float2 y = *(const float2*)(old_act + (size_t)f * DIM + d);
        dot += x.x * y.x + x.y * y.y;
        nx  += x.x * x.x + x.y * x.y;
        ny  += y.x * y.x + y.y * y.y;
    }

    // --- histogram over concatenated edge lists ---
    int e_tot = e_sub + e_sup;
    for (int i = tid; i < e_tot; i += stride) {
        int r = (i < e_sub) ? sub_rows[i] : (nrows + sup_rows[i - e_sub]);
        atomicAdd(&cnt[r], 1);
    }

    // --- block-reduce sim ---
    for (int off = 32; off > 0; off >>= 1) {
        dot += __shfl_down(dot, off, 64);
        nx  += __shfl_down(nx,  off, 64);
        ny  += __shfl_down(ny,  off, 64);
    }
    __shared__ float s[3][4];
    int lane = threadIdx.x & 63;
    int wv   = threadIdx.x >> 6;
    if (lane == 0) { s[0][wv] = dot; s[1][wv] = nx; s[2][wv] = ny; }
    __syncthreads();
    if (threadIdx.x == 0) {
        float D = 0.f, NX = 0.f, NY = 0.f;
        for (int w = 0; w < 4; ++w) { D += s[0][w]; NX += s[1][w]; NY += s[2][w]; }
        partials[blockIdx.x * 3 + 0] = D;
        partials[blockIdx.x * 3 + 1] = NX;
        partials[blockIdx.x * 3 + 2] = NY;
    }
}

__global__ void finalize_kernel(const float* __restrict__ partials,
                                float* __restrict__ out_sim) {
    double dot = 0.0, nx = 0.0, ny = 0.0;
    for (int i = threadIdx.x; i < SIM_BLOCKS; i += 64) {
        dot += (double)partials[i * 3 + 0];
        nx  += (double)partials[i * 3 + 1];
        ny  += (double)partials[i * 3 + 2];
    }
    for (int off = 32; off > 0; off >>= 1) {
        dot += __shfl_down(dot, off, 64);
        nx  += __shfl_down(nx,  off, 64);
        ny  += __shfl_down(ny,  off, 64);
    }
    if (threadIdx.x == 0)
        *out_sim = (float)(dot / (sqrt(nx) * sqrt(ny)));
}

// ---------------- hierarchical scan over m = 2*nrows counts ----------------
__global__ void scanA_kernel(const int* __restrict__ cnt, int* __restrict__ tmp,
                             int* __restrict__ bsum, int m) {
    __shared__ int s[256];
    int i = blockIdx.x * 256 + threadIdx.x;
    int v = (i < m) ? cnt[i] : 0;
    s[threadIdx.x] = v;
    __syncthreads();
    for (int d = 1; d < 256; d <<= 1) {
        int t = (threadIdx.x >= (unsigned)d) ? s[threadIdx.x - d] : 0;
        __syncthreads();
        s[threadIdx.x] += t;
        __syncthreads();
    }
    if (i < m) tmp[i] = s[threadIdx.x] - v;          // exclusive within block
    if (threadIdx.x == 255) bsum[blockIdx.x] = s[255];
}

__global__ void scanB_kernel(int* __restrict__ bsum, int* __restrict__ boff, int nb) {
    __shared__ int s[512];
    int v = (threadIdx.x < nb) ? bsum[threadIdx.x] : 0;
    s[threadIdx.x] = v;
    __syncthreads();
    for (int d = 1; d < 512; d <<= 1) {
        int t = (threadIdx.x >= (unsigned)d) ? s[threadIdx.x - d] : 0;
        __syncthreads();
        s[threadIdx.x] += t;
        __syncthreads();
    }
    if (threadIdx.x < nb) boff[threadIdx.x] = s[threadIdx.x] - v;  // exclusive
}

// writes off[] and cur[] (cur may alias tmp)
__global__ void scanC_kernel(const int* tmp, const int* __restrict__ boff,
                             int* __restrict__ off, int* cur, int m, int e_tot) {
    int i = blockIdx.x * 256 + threadIdx.x;
    if (i < m) {
        int o = tmp[i] + boff[i >> 8];
        off[i] = o;
        cur[i] = o;
    }
    if (i == 0) off[m] = e_tot;
}

// ---------------- fused scatter over both edge lists ----------------
__global__ void scatter_kernel(const int* __restrict__ sub_rows, const int* __restrict__ sub_cols,
                               const float* __restrict__ sub_vals, int e_sub,
                               const int* __restrict__ sup_rows, const int* __restrict__ sup_cols,
                               const float* __restrict__ sup_vals, int e_sup,
                               int* __restrict__ cur, int2* __restrict__ pk, int nrows) {
    int i = blockIdx.x * blockDim.x + threadIdx.x;
    int e_tot = e_sub + e_sup;
    if (i >= e_tot) return;
    int r, c; float v;
    if (i < e_sub) {
        r = sub_rows[i]; c = sub_cols[i]; v = sub_vals[i];
    } else {
        int k = i - e_sub;
        r = nrows + sup_rows[k]; c = sup_cols[k]; v = sup_vals[k];
    }
    int pos = atomicAdd(&cur[r], 1);
    pk[pos] = make_int2(c, __float_as_int(v));
}

// ---------------- per-row accumulate: one wave per row, zero output atomics ----------
__global__ void row_kernel(const int* __restrict__ off, const int2* __restrict__ pk,
                           const float* __restrict__ inputs, const float* __restrict__ old_act,
                           const int* __restrict__ fields, float* __restrict__ out, int nrows) {
    int wv = threadIdx.x >> 6, lane = threadIdx.x & 63;
    int r = blockIdx.x * (blockDim.x >> 6) + wv;
    if (r >= nrows) return;
    int d0 = lane * 2;
    float a0 = 0.f, a1 = 0.f;

    // sub edges: pk[off[r] .. off[r+1])
    {
        int b = off[r], e = off[r + 1];
        if (b < e) {
            int2 p = pk[b];
            for (int j = b; j < e; ++j) {
                int2 pn = (j + 1 < e) ? pk[j + 1] : p;   // pipeline next pk load
                int c = p.x; float v = __int_as_float(p.y);
                int f = fields[c];
                float2 x = *(const float2*)(inputs  + (size_t)c * DIM + d0);
                float2 y = *(const float2*)(old_act + (size_t)f * DIM + d0);
                a0 += v * (x.x - y.x);
                a1 += v * (x.y - y.y);
                p = pn;
            }
        }
    }
    // sup edges: pk[off[nrows+r] .. off[nrows+r+1])
    {
        int b = off[nrows + r], e = off[nrows + r + 1];
        if (b < e) {
            int2 p = pk[b];
            for (int j = b; j < e; ++j) {
                int2 pn = (j + 1 < e) ? pk[j + 1] : p;
                int c = p.x; float v = __int_as_float(p.y);
                float2 y = *(const float2*)(old_act + (size_t)c * DIM + d0);
                a0 += v * y.x;
                a1 += v * y.y;
                p = pn;
            }
        }
    }
    *(float2*)(out + (size_t)r * DIM + d0) = make_float2(a0, a1);
}

// ---------------- fallback (atomic path, if ws too small) ----------
__global__ void zero_out_kernel(float* __restrict__ out, int n) {
    int i = blockIdx.x * blockDim.x + threadIdx.x;
    if (i < n) out[i] = 0.f;
}
__global__ void spmm_sub_atomic(const int* __restrict__ rows, const int* __restrict__ cols,
                                const float* __restrict__ vals, const float* __restrict__ inputs,
                                const float* __restrict__ old_act, const int* __restrict__ fields,
                                float* __restrict__ out, int ne) {
    int t = blockIdx.x * blockDim.x + threadIdx.x;
    int e = t >> 6, lane = t & 63;
    if (e >= ne) return;
    int r = rows[e], c = cols[e];
    float v = vals[e];
    int f = fields[c];
    int d0 = lane * 2;
    const float2 x = *(const float2*)(inputs  + (size_t)c * DIM + d0);
    const float2 y = *(const float2*)(old_act + (size_t)f * DIM + d0);
    float* o = out + (size_t)r * DIM + d0;
    atomicAdd(o,     v * (x.x - y.x));
    atomicAdd(o + 1, v * (x.y - y.y));
}
__global__ void spmm_sup_atomic(const int* __restrict__ rows, const int* __restrict__ cols,
                                const float* __restrict__ vals, const float* __restrict__ old_act,
                                float* __restrict__ out, int ne) {
    int t = blockIdx.x * blockDim.x + threadIdx.x;
    int e = t >> 6, lane = t & 63;
    if (e >= ne) return;
    int r = rows[e], c = cols[e];
    float v = vals[e];
    int d0 = lane * 2;
    const float2 y = *(const float2*)(old_act + (size_t)c * DIM + d0);
    float* o = out + (size_t)r * DIM + d0;
    atomicAdd(o,     v * y.x);
    atomicAdd(o + 1, v * y.y);
}

extern "C" void kernel_launch(void* const* d_in, const int* in_sizes, int n_in,
                              void* d_out, int out_size, void* d_ws, size_t ws_size,
                              hipStream_t stream) {
    const float* inputs   = (const float*)d_in[0];
    const float* old_act  = (const float*)d_in[1];
    const int*   fields   = (const int*)d_in[2];
    const int*   sub_rows = (const int*)d_in[3];
    const int*   sub_cols = (const int*)d_in[4];
    const float* sub_vals = (const float*)d_in[5];
    const int*   sup_rows = (const int*)d_in[6];
    const int*   sup_cols = (const int*)d_in[7];
    const float* sup_vals = (const float*)d_in[8];

    const int n     = in_sizes[0];       // BATCH * DIM
    const int nrows = n / DIM;           // BATCH
    const int e_sub = in_sizes[3];
    const int e_sup = in_sizes[6];
    const int e_tot = e_sub + e_sup;
    const int m     = 2 * nrows;         // concatenated count array length
    const int nblkA = (m + 255) / 256;   // scan blocks (<= 512)

    float*  out = (float*)d_out;
    char*   ws  = (char*)d_ws;

    // ---- workspace layout ----
    size_t off_part = 0;                                       // partials f32[SIM_BLOCKS*3]
    size_t off_cnt  = (SIM_BLOCKS * 3 * 4 + 63) & ~(size_t)63; // cnt  [m]
    size_t off_tmp  = off_cnt + (size_t)m * 4;                 // tmp==cur [m]
    size_t off_offs = off_tmp + (size_t)m * 4;                 // off [m+1]
    size_t off_bsum = off_offs + (size_t)(m + 1) * 4;          // bsum [nblkA]
    size_t off_boff = off_bsum + (size_t)nblkA * 4;            // boff [nblkA]
    size_t off_pk   = (off_boff + (size_t)nblkA * 4 + 7) & ~(size_t)7;  // int2[e_tot]
    size_t need     = off_pk + (size_t)e_tot * 8;

    float* partials = (float*)(ws + off_part);

    if (ws_size >= need && nblkA <= 512) {
        int*  cnt  = (int*)(ws + off_cnt);
        int*  tmp  = (int*)(ws + off_tmp);    // aliased as cur after scanC
        int*  offs = (int*)(ws + off_offs);
        int*  bsum = (int*)(ws + off_bsum);
        int*  boff = (int*)(ws + off_boff);
        int2* pk   = (int2*)(ws + off_pk);

        hipMemsetAsync(cnt, 0, (size_t)m * 4, stream);

        prep_kernel<<<SIM_BLOCKS, 256, 0, stream>>>(
            inputs, old_act, fields, sub_rows, e_sub, sup_rows, e_sup,
            cnt, partials, nrows, n / 2);

        scanA_kernel<<<nblkA, 256, 0, stream>>>(cnt, tmp, bsum, m);
        scanB_kernel<<<1, 512, 0, stream>>>(bsum, boff, nblkA);
        scanC_kernel<<<nblkA, 256, 0, stream>>>(tmp, boff, offs, tmp, m, e_tot);

        scatter_kernel<<<(e_tot + 255) / 256, 256, 0, stream>>>(
            sub_rows, sub_cols, sub_vals, e_sub,
            sup_rows, sup_cols, sup_vals, e_sup, tmp, pk, nrows);

        row_kernel<<<(nrows + 3) / 4, 256, 0, stream>>>(offs, pk, inputs, old_act,
                                                        fields, out, nrows);
    } else {
        // fallback: atomic scatter path (plus sim via prep-less route)
        prep_kernel<<<SIM_BLOCKS, 256, 0, stream>>>(
            inputs, old_act, fields, sub_rows, 0, sup_rows, 0,
            (int*)(ws + off_cnt), partials, nrows, n / 2);  // hist with 0 edges = sim only
        zero_out_kernel<<<(n + 255) / 256, 256, 0, stream>>>(out, n);
        {
            long long threads = (long long)e_sub * 64;
            spmm_sub_atomic<<<(int)((threads + 255) / 256), 256, 0, stream>>>(
                sub_rows, sub_cols, sub_vals, inputs, old_act, fields, out, e_sub);
        }
        {
            long long threads = (long long)e_sup * 64;
            spmm_sup_atomic<<<(int)((threads + 255) / 256), 256, 0, stream>>>(
                sup_rows, sup_cols, sup_vals, old_act, out, e_sup);
        }
    }

    finalize_kernel<<<1, 64, 0, stream>>>(partials, out + n);
}